// Round 1
// baseline (231.796 us; speedup 1.0000x reference)
//
#include <hip/hip_runtime.h>
#include <hip/hip_bf16.h>
#include <stdint.h>

#define BATCH  2
#define SEQ    2048
#define DMODEL 1024
#define NHEAD  16
#define DHEAD  64

typedef unsigned short u16;
typedef __attribute__((ext_vector_type(8))) short bf16x8;
typedef __attribute__((ext_vector_type(4))) float f32x4;

__device__ __forceinline__ u16 f2bf(float x) {
    union { float f; uint32_t u; } v; v.f = x;
    uint32_t r = v.u + 0x7fffu + ((v.u >> 16) & 1u);
    return (u16)(r >> 16);
}

__device__ __forceinline__ void gload_lds16(const void* g, void* l) {
    __builtin_amdgcn_global_load_lds(
        (const __attribute__((address_space(1))) uint32_t*)(uintptr_t)g,
        (__attribute__((address_space(3))) uint32_t*)(uintptr_t)l,
        16, 0, 0);
}

__device__ __forceinline__ f32x4 mfma16(bf16x8 a, bf16x8 b, f32x4 c) {
    return __builtin_amdgcn_mfma_f32_16x16x32_bf16(a, b, c, 0, 0, 0);
}

// ---------------------------------------------------------------------------
// f32 -> bf16 conversion for 3 activations + 4 weights (grid.y = segment)
// ---------------------------------------------------------------------------
__global__ __launch_bounds__(256) void cvt7_kernel(
    const float* s0, const float* s1, const float* s2, const float* s3,
    const float* s4, const float* s5, const float* s6,
    u16* d0, u16* d1, u16* d2, u16* d3, u16* d4, u16* d5, u16* d6)
{
    const float* s; u16* d; size_t n;
    switch (blockIdx.y) {
        case 0: s = s0; d = d0; n = (size_t)BATCH * SEQ * DMODEL; break;
        case 1: s = s1; d = d1; n = (size_t)BATCH * SEQ * DMODEL; break;
        case 2: s = s2; d = d2; n = (size_t)BATCH * SEQ * DMODEL; break;
        case 3: s = s3; d = d3; n = (size_t)DMODEL * DMODEL; break;
        case 4: s = s4; d = d4; n = (size_t)DMODEL * DMODEL; break;
        case 5: s = s5; d = d5; n = (size_t)DMODEL * DMODEL; break;
        default: s = s6; d = d6; n = (size_t)DMODEL * DMODEL; break;
    }
    size_t i = ((size_t)blockIdx.x * 256 + threadIdx.x) * 8;
    if (i >= n) return;
    float4 a = *(const float4*)(s + i);
    float4 b = *(const float4*)(s + i + 4);
    union { uint4 v; u16 e[8]; } u;
    u.e[0] = f2bf(a.x); u.e[1] = f2bf(a.y); u.e[2] = f2bf(a.z); u.e[3] = f2bf(a.w);
    u.e[4] = f2bf(b.x); u.e[5] = f2bf(b.y); u.e[6] = f2bf(b.z); u.e[7] = f2bf(b.w);
    *(uint4*)(d + i) = u.v;
}

// ---------------------------------------------------------------------------
// Shared 128x128 BT-GEMM core (m97 structure): C = A (MxK) * B^T (NxK row-major)
// ---------------------------------------------------------------------------
__device__ __forceinline__ void gemm_core_128(
    const u16* __restrict__ A, const u16* __restrict__ Bm, int K,
    int brow, int bcol, u16* As, u16* Bs, f32x4 (&acc)[4][4])
{
    const int tid  = threadIdx.x;
    const int lane = tid & 63;
    const int wr   = ((tid >> 6) >> 1) * 64;
    const int wc   = ((tid >> 6) & 1) * 64;
    const int srow = tid >> 2;
    const int scol = (tid & 3) * 8;
    const int fr   = lane & 15;
    const int fk   = (lane >> 4) * 8;

    for (int k0 = 0; k0 < K; k0 += 32) {
        gload_lds16(A  + (size_t)(brow + srow) * K + k0 + scol,       As + srow * 32 + scol);
        gload_lds16(A  + (size_t)(brow + 64 + srow) * K + k0 + scol,  As + (64 + srow) * 32 + scol);
        gload_lds16(Bm + (size_t)(bcol + srow) * K + k0 + scol,       Bs + srow * 32 + scol);
        gload_lds16(Bm + (size_t)(bcol + 64 + srow) * K + k0 + scol,  Bs + (64 + srow) * 32 + scol);
        __syncthreads();
        bf16x8 af[4], bfv[4];
        #pragma unroll
        for (int i = 0; i < 4; ++i) {
            af[i]  = *(const bf16x8*)(As + (wr + i * 16 + fr) * 32 + fk);
            bfv[i] = *(const bf16x8*)(Bs + (wc + i * 16 + fr) * 32 + fk);
        }
        #pragma unroll
        for (int am = 0; am < 4; ++am)
            #pragma unroll
            for (int bn = 0; bn < 4; ++bn)
                acc[am][bn] = mfma16(af[am], bfv[bn], acc[am][bn]);
        __syncthreads();
    }
}

// QKV projection: z selects (X, W, out); scale folds 1/sqrt(dk) into Q
__global__ __launch_bounds__(256) void gemm_qkv_kernel(
    const u16* __restrict__ Xq, const u16* __restrict__ Xk, const u16* __restrict__ Xv,
    const u16* __restrict__ Wq, const u16* __restrict__ Wk, const u16* __restrict__ Wv,
    u16* __restrict__ Qo, u16* __restrict__ Ko, u16* __restrict__ Vo,
    int M, int Nn, int K)
{
    __shared__ u16 As[128 * 32];
    __shared__ u16 Bs[128 * 32];
    const int z = blockIdx.z;
    const u16* A  = (z == 0) ? Xq : (z == 1) ? Xk : Xv;
    const u16* Bm = (z == 0) ? Wq : (z == 1) ? Wk : Wv;
    u16* D        = (z == 0) ? Qo : (z == 1) ? Ko : Vo;
    const float scale = (z == 0) ? 0.125f : 1.0f;

    const int brow = blockIdx.y * 128;
    const int bcol = blockIdx.x * 128;
    f32x4 acc[4][4];
    #pragma unroll
    for (int am = 0; am < 4; ++am)
        #pragma unroll
        for (int bn = 0; bn < 4; ++bn)
            acc[am][bn] = (f32x4){0.f, 0.f, 0.f, 0.f};

    gemm_core_128(A, Bm, K, brow, bcol, As, Bs, acc);

    const int lane = threadIdx.x & 63;
    const int wr = ((threadIdx.x >> 6) >> 1) * 64;
    const int wc = ((threadIdx.x >> 6) & 1) * 64;
    const int fr = lane & 15;
    const int fj4 = (lane >> 4) * 4;
    #pragma unroll
    for (int am = 0; am < 4; ++am)
        #pragma unroll
        for (int bn = 0; bn < 4; ++bn)
            #pragma unroll
            for (int j = 0; j < 4; ++j) {
                int row = brow + wr + am * 16 + fj4 + j;
                int col = bcol + wc + bn * 16 + fr;
                D[(size_t)row * Nn + col] = f2bf(acc[am][bn][j] * scale);
            }
}

// Output projection + bias + residual, fp32 out
__global__ __launch_bounds__(256) void gemm_out_kernel(
    const u16* __restrict__ A, const u16* __restrict__ Bm,
    const float* __restrict__ bias, const float* __restrict__ resid,
    float* __restrict__ D, int M, int Nn, int K)
{
    __shared__ u16 As[128 * 32];
    __shared__ u16 Bs[128 * 32];
    const int brow = blockIdx.y * 128;
    const int bcol = blockIdx.x * 128;
    f32x4 acc[4][4];
    #pragma unroll
    for (int am = 0; am < 4; ++am)
        #pragma unroll
        for (int bn = 0; bn < 4; ++bn)
            acc[am][bn] = (f32x4){0.f, 0.f, 0.f, 0.f};

    gemm_core_128(A, Bm, K, brow, bcol, As, Bs, acc);

    const int lane = threadIdx.x & 63;
    const int wr = ((threadIdx.x >> 6) >> 1) * 64;
    const int wc = ((threadIdx.x >> 6) & 1) * 64;
    const int fr = lane & 15;
    const int fj4 = (lane >> 4) * 4;
    #pragma unroll
    for (int am = 0; am < 4; ++am)
        #pragma unroll
        for (int bn = 0; bn < 4; ++bn)
            #pragma unroll
            for (int j = 0; j < 4; ++j) {
                int row = brow + wr + am * 16 + fj4 + j;
                int col = bcol + wc + bn * 16 + fr;
                D[(size_t)row * Nn + col] = acc[am][bn][j] + bias[col] + resid[(size_t)row * Nn + col];
            }
}

// ---------------------------------------------------------------------------
// Flash attention: block = (b,h, 128 q-rows), 4 waves x 32 q-rows, KV tile 64
// ---------------------------------------------------------------------------
__global__ __launch_bounds__(256) void attn_kernel(
    const u16* __restrict__ Qb, const u16* __restrict__ Kb, const u16* __restrict__ Vb,
    u16* __restrict__ AO)
{
    __shared__ u16 Ks [64 * 72];
    __shared__ u16 Vts[64 * 72];   // V transposed: [d][kv]
    __shared__ u16 Ps [128 * 72];

    const int tid  = threadIdx.x;
    const int lane = tid & 63;
    const int wave = tid >> 6;
    const int bh   = blockIdx.y;
    const size_t rowbase = (size_t)(bh >> 4) * SEQ;
    const int colbase = (bh & 15) * DHEAD;
    const int q0 = blockIdx.x * 128;
    const int fr  = lane & 15;
    const int fk  = (lane >> 4) * 8;
    const int fj4 = (lane >> 4) * 4;
    const int qw  = wave * 32;

    // Q fragments hoisted to registers (scale already folded into Q)
    bf16x8 qf[2][2];
    #pragma unroll
    for (int am = 0; am < 2; ++am)
        #pragma unroll
        for (int kc = 0; kc < 2; ++kc)
            qf[am][kc] = *(const bf16x8*)(Qb + (rowbase + q0 + qw + am * 16 + fr) * DMODEL
                                             + colbase + kc * 32 + fk);

    f32x4 oacc[2][4];
    float mrun[2][4], lrun[2][4];
    #pragma unroll
    for (int am = 0; am < 2; ++am) {
        #pragma unroll
        for (int dn = 0; dn < 4; ++dn) oacc[am][dn] = (f32x4){0.f, 0.f, 0.f, 0.f};
        #pragma unroll
        for (int j = 0; j < 4; ++j) { mrun[am][j] = -1e30f; lrun[am][j] = 0.f; }
    }

    for (int kv0 = 0; kv0 < SEQ; kv0 += 64) {
        __syncthreads();
        // stage K (vector) and V^T (scalar transpose) tiles
        #pragma unroll
        for (int p = 0; p < 2; ++p) {
            int idx = p * 256 + tid;
            int r = idx >> 3, c = (idx & 7) << 3;
            *(uint4*)(Ks + r * 72 + c) =
                *(const uint4*)(Kb + (rowbase + kv0 + r) * DMODEL + colbase + c);
            union { uint4 v; u16 e[8]; } u;
            u.v = *(const uint4*)(Vb + (rowbase + kv0 + r) * DMODEL + colbase + c);
            #pragma unroll
            for (int jj = 0; jj < 8; ++jj) Vts[(c + jj) * 72 + r] = u.e[jj];
        }
        __syncthreads();

        // S = Q * K^T  (per wave: 32 q-rows x 64 kv)
        f32x4 sacc[2][4];
        #pragma unroll
        for (int am = 0; am < 2; ++am)
            #pragma unroll
            for (int bn = 0; bn < 4; ++bn)
                sacc[am][bn] = (f32x4){0.f, 0.f, 0.f, 0.f};
        bf16x8 kf[4][2];
        #pragma unroll
        for (int bn = 0; bn < 4; ++bn)
            #pragma unroll
            for (int kc = 0; kc < 2; ++kc)
                kf[bn][kc] = *(const bf16x8*)(Ks + (bn * 16 + fr) * 72 + kc * 32 + fk);
        #pragma unroll
        for (int am = 0; am < 2; ++am)
            #pragma unroll
            for (int bn = 0; bn < 4; ++bn)
                #pragma unroll
                for (int kc = 0; kc < 2; ++kc)
                    sacc[am][bn] = mfma16(qf[am][kc], kf[bn][kc], sacc[am][bn]);

        // online softmax (wave-parallel: each q-row lives in one 16-lane group)
        #pragma unroll
        for (int am = 0; am < 2; ++am)
            #pragma unroll
            for (int j = 0; j < 4; ++j) {
                float mx = fmaxf(fmaxf(sacc[am][0][j], sacc[am][1][j]),
                                 fmaxf(sacc[am][2][j], sacc[am][3][j]));
                mx = fmaxf(mx, __shfl_xor(mx, 1));
                mx = fmaxf(mx, __shfl_xor(mx, 2));
                mx = fmaxf(mx, __shfl_xor(mx, 4));
                mx = fmaxf(mx, __shfl_xor(mx, 8));
                float mold = mrun[am][j];
                float mnew = fmaxf(mold, mx);
                float alpha = __expf(mold - mnew);
                float psum = 0.f;
                int pr = qw + am * 16 + fj4 + j;
                #pragma unroll
                for (int bn = 0; bn < 4; ++bn) {
                    float p = __expf(sacc[am][bn][j] - mnew);
                    psum += p;
                    Ps[pr * 72 + bn * 16 + fr] = f2bf(p);
                }
                psum += __shfl_xor(psum, 1);
                psum += __shfl_xor(psum, 2);
                psum += __shfl_xor(psum, 4);
                psum += __shfl_xor(psum, 8);
                lrun[am][j] = lrun[am][j] * alpha + psum;
                mrun[am][j] = mnew;
                #pragma unroll
                for (int dn = 0; dn < 4; ++dn) oacc[am][dn][j] *= alpha;
            }
        __syncthreads();

        // O += P * V
        bf16x8 pf[2][2], vf[4][2];
        #pragma unroll
        for (int am = 0; am < 2; ++am)
            #pragma unroll
            for (int kc = 0; kc < 2; ++kc)
                pf[am][kc] = *(const bf16x8*)(Ps + (qw + am * 16 + fr) * 72 + kc * 32 + fk);
        #pragma unroll
        for (int dn = 0; dn < 4; ++dn)
            #pragma unroll
            for (int kc = 0; kc < 2; ++kc)
                vf[dn][kc] = *(const bf16x8*)(Vts + (dn * 16 + fr) * 72 + kc * 32 + fk);
        #pragma unroll
        for (int am = 0; am < 2; ++am)
            #pragma unroll
            for (int dn = 0; dn < 4; ++dn)
                #pragma unroll
                for (int kc = 0; kc < 2; ++kc)
                    oacc[am][dn] = mfma16(pf[am][kc], vf[dn][kc], oacc[am][dn]);
    }

    // epilogue: O / l
    #pragma unroll
    for (int am = 0; am < 2; ++am) {
        float inv[4];
        #pragma unroll
        for (int j = 0; j < 4; ++j) inv[j] = 1.f / lrun[am][j];
        #pragma unroll
        for (int dn = 0; dn < 4; ++dn)
            #pragma unroll
            for (int j = 0; j < 4; ++j) {
                int row = q0 + qw + am * 16 + fj4 + j;
                AO[(rowbase + row) * DMODEL + colbase + dn * 16 + fr] =
                    f2bf(oacc[am][dn][j] * inv[j]);
            }
    }
}

// ---------------------------------------------------------------------------
extern "C" void kernel_launch(void* const* d_in, const int* in_sizes, int n_in,
                              void* d_out, int out_size, void* d_ws, size_t ws_size,
                              hipStream_t stream)
{
    const float* q_f  = (const float*)d_in[0];
    const float* k_f  = (const float*)d_in[1];
    const float* v_f  = (const float*)d_in[2];
    const float* Wq_f = (const float*)d_in[3];
    const float* Wk_f = (const float*)d_in[4];
    const float* Wv_f = (const float*)d_in[5];
    const float* Wo_f = (const float*)d_in[6];
    const float* bo_f = (const float*)d_in[7];

    char* ws = (char*)d_ws;
    const size_t ACT = (size_t)BATCH * SEQ * DMODEL * sizeof(u16);   // 8 MB
    const size_t WSZ = (size_t)DMODEL * DMODEL * sizeof(u16);        // 2 MB
    u16* Xq  = (u16*)(ws);
    u16* Xk  = (u16*)(ws + ACT);
    u16* Xv  = (u16*)(ws + 2 * ACT);
    u16* Wqb = (u16*)(ws + 3 * ACT);
    u16* Wkb = (u16*)(ws + 3 * ACT + WSZ);
    u16* Wvb = (u16*)(ws + 3 * ACT + 2 * WSZ);
    u16* Wob = (u16*)(ws + 3 * ACT + 3 * WSZ);
    u16* Qb  = (u16*)(ws + 3 * ACT + 4 * WSZ);
    u16* Kb  = (u16*)(ws + 4 * ACT + 4 * WSZ);
    u16* Vb  = (u16*)(ws + 5 * ACT + 4 * WSZ);
    u16* AO  = (u16*)(ws + 6 * ACT + 4 * WSZ);   // total 7*ACT + 4*WSZ = 64 MB

    const int M = BATCH * SEQ;      // 4096
    const int Nn = DMODEL;          // 1024
    const int K = DMODEL;           // 1024

    cvt7_kernel<<<dim3(2048, 7, 1), 256, 0, stream>>>(
        q_f, k_f, v_f, Wq_f, Wk_f, Wv_f, Wo_f,
        Xq, Xk, Xv, Wqb, Wkb, Wvb, Wob);

    gemm_qkv_kernel<<<dim3(Nn / 128, M / 128, 3), 256, 0, stream>>>(
        Xq, Xk, Xv, Wqb, Wkb, Wvb, Qb, Kb, Vb, M, Nn, K);

    attn_kernel<<<dim3(SEQ / 128, BATCH * NHEAD, 1), 256, 0, stream>>>(Qb, Kb, Vb, AO);

    gemm_out_kernel<<<dim3(Nn / 128, M / 128, 1), 256, 0, stream>>>(
        AO, Wob, bo_f, q_f, (float*)d_out, M, Nn, K);
}

// Round 2
// 214.070 us; speedup vs baseline: 1.0828x; 1.0828x over previous
//
#include <hip/hip_runtime.h>
#include <hip/hip_bf16.h>
#include <stdint.h>

#define BATCH  2
#define SEQ    2048
#define DMODEL 1024
#define NHEAD  16
#define DHEAD  64

typedef unsigned short u16;
typedef __attribute__((ext_vector_type(8))) short bf16x8;
typedef __attribute__((ext_vector_type(4))) float f32x4;

__device__ __forceinline__ u16 f2bf(float x) {
    union { float f; uint32_t u; } v; v.f = x;
    uint32_t r = v.u + 0x7fffu + ((v.u >> 16) & 1u);
    return (u16)(r >> 16);
}

__device__ __forceinline__ void gload_lds16(const void* g, void* l) {
    __builtin_amdgcn_global_load_lds(
        (const __attribute__((address_space(1))) uint32_t*)(uintptr_t)g,
        (__attribute__((address_space(3))) uint32_t*)(uintptr_t)l,
        16, 0, 0);
}

__device__ __forceinline__ f32x4 mfma16(bf16x8 a, bf16x8 b, f32x4 c) {
    return __builtin_amdgcn_mfma_f32_16x16x32_bf16(a, b, c, 0, 0, 0);
}

// ---------------------------------------------------------------------------
// f32 -> bf16 conversion for 3 activations + 4 weights (grid.y = segment)
// ---------------------------------------------------------------------------
__global__ __launch_bounds__(256) void cvt7_kernel(
    const float* s0, const float* s1, const float* s2, const float* s3,
    const float* s4, const float* s5, const float* s6,
    u16* d0, u16* d1, u16* d2, u16* d3, u16* d4, u16* d5, u16* d6)
{
    const float* s; u16* d; size_t n;
    switch (blockIdx.y) {
        case 0: s = s0; d = d0; n = (size_t)BATCH * SEQ * DMODEL; break;
        case 1: s = s1; d = d1; n = (size_t)BATCH * SEQ * DMODEL; break;
        case 2: s = s2; d = d2; n = (size_t)BATCH * SEQ * DMODEL; break;
        case 3: s = s3; d = d3; n = (size_t)DMODEL * DMODEL; break;
        case 4: s = s4; d = d4; n = (size_t)DMODEL * DMODEL; break;
        case 5: s = s5; d = d5; n = (size_t)DMODEL * DMODEL; break;
        default: s = s6; d = d6; n = (size_t)DMODEL * DMODEL; break;
    }
    size_t i = ((size_t)blockIdx.x * 256 + threadIdx.x) * 8;
    if (i >= n) return;
    float4 a = *(const float4*)(s + i);
    float4 b = *(const float4*)(s + i + 4);
    union { uint4 v; u16 e[8]; } u;
    u.e[0] = f2bf(a.x); u.e[1] = f2bf(a.y); u.e[2] = f2bf(a.z); u.e[3] = f2bf(a.w);
    u.e[4] = f2bf(b.x); u.e[5] = f2bf(b.y); u.e[6] = f2bf(b.z); u.e[7] = f2bf(b.w);
    *(uint4*)(d + i) = u.v;
}

// ---------------------------------------------------------------------------
// Shared 128x128 BT-GEMM core (m97 structure): C = A (MxK) * B^T (NxK row-major)
// ---------------------------------------------------------------------------
__device__ __forceinline__ void gemm_core_128(
    const u16* __restrict__ A, const u16* __restrict__ Bm, int K,
    int brow, int bcol, u16* As, u16* Bs, f32x4 (&acc)[4][4])
{
    const int tid  = threadIdx.x;
    const int lane = tid & 63;
    const int wr   = ((tid >> 6) >> 1) * 64;
    const int wc   = ((tid >> 6) & 1) * 64;
    const int srow = tid >> 2;
    const int scol = (tid & 3) * 8;
    const int fr   = lane & 15;
    const int fk   = (lane >> 4) * 8;

    for (int k0 = 0; k0 < K; k0 += 32) {
        gload_lds16(A  + (size_t)(brow + srow) * K + k0 + scol,       As + srow * 32 + scol);
        gload_lds16(A  + (size_t)(brow + 64 + srow) * K + k0 + scol,  As + (64 + srow) * 32 + scol);
        gload_lds16(Bm + (size_t)(bcol + srow) * K + k0 + scol,       Bs + srow * 32 + scol);
        gload_lds16(Bm + (size_t)(bcol + 64 + srow) * K + k0 + scol,  Bs + (64 + srow) * 32 + scol);
        __syncthreads();
        bf16x8 af[4], bfv[4];
        #pragma unroll
        for (int i = 0; i < 4; ++i) {
            af[i]  = *(const bf16x8*)(As + (wr + i * 16 + fr) * 32 + fk);
            bfv[i] = *(const bf16x8*)(Bs + (wc + i * 16 + fr) * 32 + fk);
        }
        #pragma unroll
        for (int am = 0; am < 4; ++am)
            #pragma unroll
            for (int bn = 0; bn < 4; ++bn)
                acc[am][bn] = mfma16(af[am], bfv[bn], acc[am][bn]);
        __syncthreads();
    }
}

// QKV projection: z selects (X, W, out); scale folds 1/sqrt(dk) into Q
__global__ __launch_bounds__(256) void gemm_qkv_kernel(
    const u16* __restrict__ Xq, const u16* __restrict__ Xk, const u16* __restrict__ Xv,
    const u16* __restrict__ Wq, const u16* __restrict__ Wk, const u16* __restrict__ Wv,
    u16* __restrict__ Qo, u16* __restrict__ Ko, u16* __restrict__ Vo,
    int M, int Nn, int K)
{
    __shared__ u16 As[128 * 32];
    __shared__ u16 Bs[128 * 32];
    const int z = blockIdx.z;
    const u16* A  = (z == 0) ? Xq : (z == 1) ? Xk : Xv;
    const u16* Bm = (z == 0) ? Wq : (z == 1) ? Wk : Wv;
    u16* D        = (z == 0) ? Qo : (z == 1) ? Ko : Vo;
    const float scale = (z == 0) ? 0.125f : 1.0f;

    const int brow = blockIdx.y * 128;
    const int bcol = blockIdx.x * 128;
    f32x4 acc[4][4];
    #pragma unroll
    for (int am = 0; am < 4; ++am)
        #pragma unroll
        for (int bn = 0; bn < 4; ++bn)
            acc[am][bn] = (f32x4){0.f, 0.f, 0.f, 0.f};

    gemm_core_128(A, Bm, K, brow, bcol, As, Bs, acc);

    const int lane = threadIdx.x & 63;
    const int wr = ((threadIdx.x >> 6) >> 1) * 64;
    const int wc = ((threadIdx.x >> 6) & 1) * 64;
    const int fr = lane & 15;
    const int fj4 = (lane >> 4) * 4;
    #pragma unroll
    for (int am = 0; am < 4; ++am)
        #pragma unroll
        for (int bn = 0; bn < 4; ++bn)
            #pragma unroll
            for (int j = 0; j < 4; ++j) {
                int row = brow + wr + am * 16 + fj4 + j;
                int col = bcol + wc + bn * 16 + fr;
                D[(size_t)row * Nn + col] = f2bf(acc[am][bn][j] * scale);
            }
}

// Output projection + bias + residual, fp32 out
__global__ __launch_bounds__(256) void gemm_out_kernel(
    const u16* __restrict__ A, const u16* __restrict__ Bm,
    const float* __restrict__ bias, const float* __restrict__ resid,
    float* __restrict__ D, int M, int Nn, int K)
{
    __shared__ u16 As[128 * 32];
    __shared__ u16 Bs[128 * 32];
    const int brow = blockIdx.y * 128;
    const int bcol = blockIdx.x * 128;
    f32x4 acc[4][4];
    #pragma unroll
    for (int am = 0; am < 4; ++am)
        #pragma unroll
        for (int bn = 0; bn < 4; ++bn)
            acc[am][bn] = (f32x4){0.f, 0.f, 0.f, 0.f};

    gemm_core_128(A, Bm, K, brow, bcol, As, Bs, acc);

    const int lane = threadIdx.x & 63;
    const int wr = ((threadIdx.x >> 6) >> 1) * 64;
    const int wc = ((threadIdx.x >> 6) & 1) * 64;
    const int fr = lane & 15;
    const int fj4 = (lane >> 4) * 4;
    #pragma unroll
    for (int am = 0; am < 4; ++am)
        #pragma unroll
        for (int bn = 0; bn < 4; ++bn)
            #pragma unroll
            for (int j = 0; j < 4; ++j) {
                int row = brow + wr + am * 16 + fj4 + j;
                int col = bcol + wc + bn * 16 + fr;
                D[(size_t)row * Nn + col] = acc[am][bn][j] + bias[col] + resid[(size_t)row * Nn + col];
            }
}

// ---------------------------------------------------------------------------
// V transpose: V[b][n][h*64+d] -> Vt[bh][d][n]  (LDS-tiled, 64x64 tiles)
// ---------------------------------------------------------------------------
__global__ __launch_bounds__(256) void vtrans_kernel(
    const u16* __restrict__ V, u16* __restrict__ Vt)
{
    __shared__ u16 T[64][66];
    const int tid = threadIdx.x;
    const int bh  = blockIdx.y;
    const int kv0 = blockIdx.x * 64;
    const size_t rowbase = (size_t)(bh >> 4) * SEQ;
    const int colbase = (bh & 15) * DHEAD;

    // load 64 kv-rows x 64 d-cols, coalesced; each thread 16 u16
    {
        const int r = tid >> 2;
        const int c = (tid & 3) * 16;
        const u16* src = V + (rowbase + kv0 + r) * DMODEL + colbase + c;
        uint4 a = *(const uint4*)(src);
        uint4 b = *(const uint4*)(src + 8);
        uint32_t* dst = (uint32_t*)&T[r][c];
        dst[0] = a.x; dst[1] = a.y; dst[2] = a.z; dst[3] = a.w;
        dst[4] = b.x; dst[5] = b.y; dst[6] = b.z; dst[7] = b.w;
    }
    __syncthreads();
    // write out transposed rows (d-major), coalesced
    {
        const int d = tid >> 2;
        const int c = (tid & 3) * 16;
        union { uint4 v; u16 e[8]; } o0, o1;
        #pragma unroll
        for (int j = 0; j < 8; ++j) o0.e[j] = T[c + j][d];
        #pragma unroll
        for (int j = 0; j < 8; ++j) o1.e[j] = T[c + 8 + j][d];
        u16* dst = Vt + (size_t)bh * DHEAD * SEQ + (size_t)d * SEQ + kv0 + c;
        *(uint4*)(dst) = o0.v;
        *(uint4*)(dst + 8) = o1.v;
    }
}

// ---------------------------------------------------------------------------
// Flash attention: block = (b,h, 128 q-rows), 4 independent waves x 32 q-rows.
// No barriers, no K/V LDS staging: K and Vt fragments read directly from
// global (L2-resident, 256 KB/head). LDS holds only the per-wave-private Ps.
// ---------------------------------------------------------------------------
__global__ __launch_bounds__(256) void attn_kernel(
    const u16* __restrict__ Qb, const u16* __restrict__ Kb, const u16* __restrict__ Vt,
    u16* __restrict__ AO)
{
    __shared__ u16 Ps[128 * 72];

    const int tid  = threadIdx.x;
    const int lane = tid & 63;
    const int wave = tid >> 6;
    const int bh   = blockIdx.y;
    const size_t rowbase = (size_t)(bh >> 4) * SEQ;
    const int colbase = (bh & 15) * DHEAD;
    const int q0 = blockIdx.x * 128;
    const int fr  = lane & 15;
    const int fk  = (lane >> 4) * 8;
    const int fj4 = (lane >> 4) * 4;
    const int qw  = wave * 32;

    const u16* Kh = Kb + rowbase * DMODEL + colbase;   // rows: kv, stride DMODEL
    const u16* Vh = Vt + (size_t)bh * DHEAD * SEQ;     // rows: d,  stride SEQ

    // Q fragments hoisted to registers (1/sqrt(dk) folded into Q projection)
    bf16x8 qf[2][2];
    #pragma unroll
    for (int am = 0; am < 2; ++am)
        #pragma unroll
        for (int kc = 0; kc < 2; ++kc)
            qf[am][kc] = *(const bf16x8*)(Qb + (rowbase + q0 + qw + am * 16 + fr) * DMODEL
                                             + colbase + kc * 32 + fk);

    f32x4 oacc[2][4];
    float mrun[2][4], lrun[2][4];
    #pragma unroll
    for (int am = 0; am < 2; ++am) {
        #pragma unroll
        for (int dn = 0; dn < 4; ++dn) oacc[am][dn] = (f32x4){0.f, 0.f, 0.f, 0.f};
        #pragma unroll
        for (int j = 0; j < 4; ++j) { mrun[am][j] = -1e30f; lrun[am][j] = 0.f; }
    }

    for (int kv0 = 0; kv0 < SEQ; kv0 += 64) {
        // K fragments straight from global (L2 hits)
        bf16x8 kf[4][2];
        #pragma unroll
        for (int bn = 0; bn < 4; ++bn)
            #pragma unroll
            for (int kc = 0; kc < 2; ++kc)
                kf[bn][kc] = *(const bf16x8*)(Kh + (size_t)(kv0 + bn * 16 + fr) * DMODEL
                                                 + kc * 32 + fk);

        // S = Q * K^T  (32 q-rows x 64 kv per wave)
        f32x4 sacc[2][4];
        #pragma unroll
        for (int am = 0; am < 2; ++am)
            #pragma unroll
            for (int bn = 0; bn < 4; ++bn)
                sacc[am][bn] = (f32x4){0.f, 0.f, 0.f, 0.f};
        #pragma unroll
        for (int am = 0; am < 2; ++am)
            #pragma unroll
            for (int bn = 0; bn < 4; ++bn)
                #pragma unroll
                for (int kc = 0; kc < 2; ++kc)
                    sacc[am][bn] = mfma16(qf[am][kc], kf[bn][kc], sacc[am][bn]);

        // issue Vt fragment loads now: softmax VALU hides their L2 latency
        bf16x8 vf[4][2];
        #pragma unroll
        for (int dn = 0; dn < 4; ++dn)
            #pragma unroll
            for (int kc = 0; kc < 2; ++kc)
                vf[dn][kc] = *(const bf16x8*)(Vh + (size_t)(dn * 16 + fr) * SEQ
                                                 + kv0 + kc * 32 + fk);

        // online softmax (wave-parallel; each q-row lives in one 16-lane group)
        #pragma unroll
        for (int am = 0; am < 2; ++am)
            #pragma unroll
            for (int j = 0; j < 4; ++j) {
                float mx = fmaxf(fmaxf(sacc[am][0][j], sacc[am][1][j]),
                                 fmaxf(sacc[am][2][j], sacc[am][3][j]));
                mx = fmaxf(mx, __shfl_xor(mx, 1));
                mx = fmaxf(mx, __shfl_xor(mx, 2));
                mx = fmaxf(mx, __shfl_xor(mx, 4));
                mx = fmaxf(mx, __shfl_xor(mx, 8));
                float mold = mrun[am][j];
                float mnew = fmaxf(mold, mx);
                float alpha = __expf(mold - mnew);
                float psum = 0.f;
                int pr = qw + am * 16 + fj4 + j;
                #pragma unroll
                for (int bn = 0; bn < 4; ++bn) {
                    float p = __expf(sacc[am][bn][j] - mnew);
                    psum += p;
                    Ps[pr * 72 + bn * 16 + fr] = f2bf(p);
                }
                psum += __shfl_xor(psum, 1);
                psum += __shfl_xor(psum, 2);
                psum += __shfl_xor(psum, 4);
                psum += __shfl_xor(psum, 8);
                lrun[am][j] = lrun[am][j] * alpha + psum;
                mrun[am][j] = mnew;
                #pragma unroll
                for (int dn = 0; dn < 4; ++dn) oacc[am][dn][j] *= alpha;
            }

        // O += P * V   (Ps is per-wave-private; lgkmcnt ordering only, no barrier)
        bf16x8 pf[2][2];
        #pragma unroll
        for (int am = 0; am < 2; ++am)
            #pragma unroll
            for (int kc = 0; kc < 2; ++kc)
                pf[am][kc] = *(const bf16x8*)(Ps + (qw + am * 16 + fr) * 72 + kc * 32 + fk);
        #pragma unroll
        for (int am = 0; am < 2; ++am)
            #pragma unroll
            for (int dn = 0; dn < 4; ++dn)
                #pragma unroll
                for (int kc = 0; kc < 2; ++kc)
                    oacc[am][dn] = mfma16(pf[am][kc], vf[dn][kc], oacc[am][dn]);
    }

    // epilogue: O / l
    #pragma unroll
    for (int am = 0; am < 2; ++am) {
        float inv[4];
        #pragma unroll
        for (int j = 0; j < 4; ++j) inv[j] = 1.f / lrun[am][j];
        #pragma unroll
        for (int dn = 0; dn < 4; ++dn)
            #pragma unroll
            for (int j = 0; j < 4; ++j) {
                int row = q0 + qw + am * 16 + fj4 + j;
                AO[(rowbase + row) * DMODEL + colbase + dn * 16 + fr] =
                    f2bf(oacc[am][dn][j] * inv[j]);
            }
    }
}

// ---------------------------------------------------------------------------
extern "C" void kernel_launch(void* const* d_in, const int* in_sizes, int n_in,
                              void* d_out, int out_size, void* d_ws, size_t ws_size,
                              hipStream_t stream)
{
    const float* q_f  = (const float*)d_in[0];
    const float* k_f  = (const float*)d_in[1];
    const float* v_f  = (const float*)d_in[2];
    const float* Wq_f = (const float*)d_in[3];
    const float* Wk_f = (const float*)d_in[4];
    const float* Wv_f = (const float*)d_in[5];
    const float* Wv2_f= (const float*)d_in[5];
    const float* Wo_f = (const float*)d_in[6];
    const float* bo_f = (const float*)d_in[7];
    (void)Wv2_f;

    char* ws = (char*)d_ws;
    const size_t ACT = (size_t)BATCH * SEQ * DMODEL * sizeof(u16);   // 8 MB
    const size_t WSZ = (size_t)DMODEL * DMODEL * sizeof(u16);        // 2 MB
    u16* Xq  = (u16*)(ws);
    u16* Xk  = (u16*)(ws + ACT);
    u16* Xv  = (u16*)(ws + 2 * ACT);
    u16* Wqb = (u16*)(ws + 3 * ACT);
    u16* Wkb = (u16*)(ws + 3 * ACT + WSZ);
    u16* Wvb = (u16*)(ws + 3 * ACT + 2 * WSZ);
    u16* Wob = (u16*)(ws + 3 * ACT + 3 * WSZ);
    u16* Qb  = (u16*)(ws + 3 * ACT + 4 * WSZ);
    u16* Kb  = (u16*)(ws + 4 * ACT + 4 * WSZ);
    u16* Vb  = (u16*)(ws + 5 * ACT + 4 * WSZ);
    u16* AO  = (u16*)(ws + 6 * ACT + 4 * WSZ);   // total 7*ACT + 4*WSZ = 64 MB
    u16* Vt  = Xq;   // alias: Xq is dead after gemm_qkv; cvt regenerates it next call

    const int M = BATCH * SEQ;      // 4096
    const int Nn = DMODEL;          // 1024
    const int K = DMODEL;           // 1024

    cvt7_kernel<<<dim3(2048, 7, 1), 256, 0, stream>>>(
        q_f, k_f, v_f, Wq_f, Wk_f, Wv_f, Wo_f,
        Xq, Xk, Xv, Wqb, Wkb, Wvb, Wob);

    gemm_qkv_kernel<<<dim3(Nn / 128, M / 128, 3), 256, 0, stream>>>(
        Xq, Xk, Xv, Wqb, Wkb, Wvb, Qb, Kb, Vb, M, Nn, K);

    vtrans_kernel<<<dim3(SEQ / 64, BATCH * NHEAD, 1), 256, 0, stream>>>(Vb, Vt);

    attn_kernel<<<dim3(SEQ / 128, BATCH * NHEAD, 1), 256, 0, stream>>>(Qb, Kb, Vt, AO);

    gemm_out_kernel<<<dim3(Nn / 128, M / 128, 1), 256, 0, stream>>>(
        AO, Wob, bo_f, q_f, (float*)d_out, M, Nn, K);
}